// Round 4
// baseline (1111.695 us; speedup 1.0000x reference)
//
#include <hip/hip_runtime.h>

#define HID 16
#define ODIM 64
#define IDIM 512
#define BKB 8          // bucket = 256 nodes (dst >> 8)
#define BKS 256
#define PTILE 4096     // edges per partition tile

// ---------------------------------------------------- bucket histogram (dst>>8)
__global__ __launch_bounds__(256) void k_bhist(const int* __restrict__ dst,
                                               int* __restrict__ bcnt, int ne, int nbk) {
    __shared__ int h[512];
    for (int t = threadIdx.x; t < 512; t += 256) h[t] = 0;
    __syncthreads();
    int stride = gridDim.x * blockDim.x;
    for (int e = blockIdx.x * blockDim.x + threadIdx.x; e < ne; e += stride)
        atomicAdd(&h[dst[e] >> BKB], 1);
    __syncthreads();
    for (int t = threadIdx.x; t < nbk; t += 256)
        if (h[t]) atomicAdd(&bcnt[t], h[t]);
}

// ------------------------------------------------- scan bucket counts (nbk<=512)
__global__ __launch_bounds__(512) void k_bscan(const int* __restrict__ bcnt,
                                               int* __restrict__ bbase,
                                               int* __restrict__ bcur, int nbk) {
    __shared__ int s[512];
    int t = threadIdx.x;
    int v = (t < nbk) ? bcnt[t] : 0;
    s[t] = v;
    __syncthreads();
    for (int off = 1; off < 512; off <<= 1) {
        int u = (t >= off) ? s[t - off] : 0;
        __syncthreads();
        s[t] += u;
        __syncthreads();
    }
    if (t < nbk) { int b = s[t] - v; bbase[t] = b; bcur[t] = b; }
}

// ------------------------------------- partition edges into buckets (staged LDS)
// packed entry: (src << 8) | (dst & 255);  src < 2^17 so fits u32.
__global__ __launch_bounds__(512) void k_part(const int* __restrict__ src,
                                              const int* __restrict__ dst,
                                              int* __restrict__ bcur,
                                              unsigned int* __restrict__ ebuf,
                                              int ne, int nbk) {
    __shared__ int h[512], sc[512], base[512], lcur[512];
    __shared__ unsigned int sval[PTILE];
    __shared__ int saddr[PTILE];
    int e0 = blockIdx.x * PTILE;
    int m = ne - e0; if (m > PTILE) m = PTILE;
    if (m <= 0) return;
    int t = threadIdx.x;
    h[t] = 0;
    __syncthreads();
    for (int k = t; k < m; k += 512) atomicAdd(&h[dst[e0 + k] >> BKB], 1);
    __syncthreads();
    int hv = h[t];
    sc[t] = hv;
    __syncthreads();
    for (int off = 1; off < 512; off <<= 1) {
        int u = (t >= off) ? sc[t - off] : 0;
        __syncthreads();
        sc[t] += u;
        __syncthreads();
    }
    base[t] = hv ? atomicAdd(&bcur[t], hv) : 0;
    lcur[t] = 0;
    __syncthreads();
    for (int k = t; k < m; k += 512) {
        int d = dst[e0 + k];
        int b = d >> BKB;
        int r = atomicAdd(&lcur[b], 1);
        int slot = sc[b] - h[b] + r;              // tile-local bucket run
        sval[slot] = ((unsigned int)src[e0 + k] << BKB) | (unsigned int)(d & (BKS - 1));
        saddr[slot] = base[b] + r;                // global dest (bucket-grouped)
    }
    __syncthreads();
    for (int k = t; k < m; k += 512) ebuf[saddr[k]] = sval[k];
}

// ----------------------------- per-bucket degree histogram -> dinv = rsqrt(d+1)
__global__ __launch_bounds__(256) void k_deg(const int* __restrict__ bbase,
                                             const int* __restrict__ bcnt,
                                             const unsigned int* __restrict__ ebuf,
                                             float* __restrict__ dinv, int n) {
    __shared__ int h[BKS];
    int bk = blockIdx.x;
    int t = threadIdx.x;
    h[t] = 0;
    __syncthreads();
    int eb = bbase[bk], ec = bcnt[bk];
    for (int k = t; k < ec; k += 256) atomicAdd(&h[ebuf[eb + k] & (BKS - 1)], 1);
    __syncthreads();
    int node = (bk << BKB) + t;
    if (node < n) dinv[node] = rsqrtf((float)(h[t] + 1));
}

// ------------------------------------------------- layer1 projection: X @ W1
// thread-per-node; W1 (512x16) in LDS; writes hs1 = (X@W1)*dinv.
__global__ __launch_bounds__(256) void k_proj1(const float* __restrict__ X,
                                               const float* __restrict__ W1,
                                               const float* __restrict__ dinv,
                                               float* __restrict__ hs1, int n) {
    __shared__ float Ws[IDIM * HID];
    for (int t = threadIdx.x; t < IDIM * HID; t += 256) Ws[t] = W1[t];
    __syncthreads();

    int i = blockIdx.x * blockDim.x + threadIdx.x;
    if (i >= n) return;

    const float4* xr = (const float4*)(X + (size_t)i * IDIM);
    float acc[HID];
#pragma unroll
    for (int j = 0; j < HID; ++j) acc[j] = 0.f;

    for (int k4 = 0; k4 < IDIM / 4; ++k4) {
        float4 x = xr[k4];
        const float* w = &Ws[k4 * 4 * HID];
#pragma unroll
        for (int j = 0; j < HID; ++j) acc[j] += x.x * w[j];
#pragma unroll
        for (int j = 0; j < HID; ++j) acc[j] += x.y * w[HID + j];
#pragma unroll
        for (int j = 0; j < HID; ++j) acc[j] += x.z * w[2 * HID + j];
#pragma unroll
        for (int j = 0; j < HID; ++j) acc[j] += x.w * w[3 * HID + j];
    }

    float di = dinv[i];
    float4* h4 = (float4*)(hs1 + (size_t)i * HID);
#pragma unroll
    for (int q = 0; q < 4; ++q) {
        float4 v;
        v.x = acc[q * 4 + 0] * di;
        v.y = acc[q * 4 + 1] * di;
        v.z = acc[q * 4 + 2] * di;
        v.w = acc[q * 4 + 3] * di;
        h4[q] = v;
    }
}

// ---------------- layer-1 aggregation: bucket-per-block, LDS f32 atomics,
// fused finalize (relu + rescale) -> hs2.  4 lanes per edge, 128 edges/iter.
__global__ __launch_bounds__(512) void k_gagg1(const int* __restrict__ bbase,
                                               const int* __restrict__ bcnt,
                                               const unsigned int* __restrict__ ebuf,
                                               const float* __restrict__ hs,
                                               const float* __restrict__ dinv,
                                               const float* __restrict__ b1,
                                               float* __restrict__ hs2, int n) {
    __shared__ float acc[BKS * 17];
    int t = threadIdx.x;
    int bk = blockIdx.x;
    int node0 = bk << BKB;
    for (int idx = t; idx < BKS * HID; idx += 512) {
        int nd = idx >> 4, j = idx & 15;
        int g = node0 + nd;
        acc[nd * 17 + j] = (g < n) ? hs[(size_t)g * HID + j] : 0.f;  // self loop
    }
    __syncthreads();
    int eb = bbase[bk], ec = bcnt[bk];
    int q = t & 3;
    for (int k = t >> 2; k < ec; k += 128) {
        unsigned int p = ebuf[eb + k];
        int dl = p & (BKS - 1);
        int s = p >> BKB;
        float4 v = ((const float4*)hs)[(size_t)s * 4 + q];
        float* a = &acc[dl * 17 + q * 4];
        atomicAdd(a + 0, v.x);
        atomicAdd(a + 1, v.y);
        atomicAdd(a + 2, v.z);
        atomicAdd(a + 3, v.w);
    }
    __syncthreads();
    for (int idx = t; idx < BKS * HID; idx += 512) {
        int nd = idx >> 4, j = idx & 15;
        int g = node0 + nd;
        if (g >= n) continue;
        float dv = dinv[g];
        float h = fmaxf(dv * acc[nd * 17 + j] + b1[j], 0.f);
        hs2[(size_t)g * HID + j] = h * dv;
    }
}

// ---------------- layer-2 aggregation + fused output projection (16 -> 64)
__global__ __launch_bounds__(512) void k_gagg2(const int* __restrict__ bbase,
                                               const int* __restrict__ bcnt,
                                               const unsigned int* __restrict__ ebuf,
                                               const float* __restrict__ hs,
                                               const float* __restrict__ dinv,
                                               const float* __restrict__ W2,
                                               const float* __restrict__ b2,
                                               float* __restrict__ out, int n) {
    __shared__ float acc[BKS * 17];
    __shared__ float Ws[HID * ODIM];
    __shared__ float bs[ODIM];
    __shared__ float dv[BKS];
    int t = threadIdx.x;
    int bk = blockIdx.x;
    int node0 = bk << BKB;
    for (int idx = t; idx < HID * ODIM; idx += 512) Ws[idx] = W2[idx];
    if (t < ODIM) bs[t] = b2[t];
    for (int idx = t; idx < BKS * HID; idx += 512) {
        int nd = idx >> 4, j = idx & 15;
        int g = node0 + nd;
        acc[nd * 17 + j] = (g < n) ? hs[(size_t)g * HID + j] : 0.f;  // self loop
    }
    if (t < BKS) {
        int g = node0 + t;
        dv[t] = (g < n) ? dinv[g] : 0.f;
    }
    __syncthreads();
    int eb = bbase[bk], ec = bcnt[bk];
    int q = t & 3;
    for (int k = t >> 2; k < ec; k += 128) {
        unsigned int p = ebuf[eb + k];
        int dl = p & (BKS - 1);
        int s = p >> BKB;
        float4 v = ((const float4*)hs)[(size_t)s * 4 + q];
        float* a = &acc[dl * 17 + q * 4];
        atomicAdd(a + 0, v.x);
        atomicAdd(a + 1, v.y);
        atomicAdd(a + 2, v.z);
        atomicAdd(a + 3, v.w);
    }
    __syncthreads();
    // 512 threads -> 8 nodes x 64 dims per iteration, 32 iterations
    int o = t & 63;
    int nsub = t >> 6;
    for (int it = 0; it < 32; ++it) {
        int nd = it * 8 + nsub;
        int g = node0 + nd;
        if (g >= n) continue;
        const float* arow = &acc[nd * 17];
        float s_ = 0.f;
#pragma unroll
        for (int k = 0; k < HID; ++k) s_ += arow[k] * Ws[k * ODIM + o];
        out[(size_t)g * ODIM + o] = dv[nd] * s_ + bs[o];
    }
}

// ---------------------------------------------------------------------- launch
extern "C" void kernel_launch(void* const* d_in, const int* in_sizes, int n_in,
                              void* d_out, int out_size, void* d_ws, size_t ws_size,
                              hipStream_t stream) {
    const int* E = (const int*)d_in[1];
    const float* X = (const float*)d_in[2];
    const float* W1 = (const float*)d_in[3];
    const float* b1 = (const float*)d_in[4];
    const float* W2 = (const float*)d_in[5];
    const float* b2 = (const float*)d_in[6];
    float* out = (float*)d_out;

    const int n = in_sizes[0];       // 100000
    const int ne = in_sizes[1] / 2;  // 3200000
    const int* src = E;
    const int* dst = E + ne;
    const int nbk = (n + BKS - 1) >> BKB;  // 391

    // workspace layout (bytes):
    //   bcnt  @ 0      | bbase @ 8 KB | bcur @ 16 KB
    //   dinv  @ 1 MB   (400 KB)
    //   ebuf  @ 2 MB   (12.8 MB)
    //   B1    @ 15 MB  (6.4 MB)  hs1
    //   B2    @ 22 MB  (6.4 MB)  hs2          -> total ~28.4 MB
    char* ws = (char*)d_ws;
    int* bcnt = (int*)ws;
    int* bbase = (int*)(ws + (8u << 10));
    int* bcur = (int*)(ws + (16u << 10));
    float* dinv = (float*)(ws + (1u << 20));
    unsigned int* ebuf = (unsigned int*)(ws + (2u << 20));
    float* B1 = (float*)(ws + (15u << 20));
    float* B2 = (float*)(ws + (22u << 20));

    hipMemsetAsync(bcnt, 0, nbk * sizeof(int), stream);
    k_bhist<<<1024, 256, 0, stream>>>(dst, bcnt, ne, nbk);
    k_bscan<<<1, 512, 0, stream>>>(bcnt, bbase, bcur, nbk);
    k_part<<<(ne + PTILE - 1) / PTILE, 512, 0, stream>>>(src, dst, bcur, ebuf, ne, nbk);
    k_deg<<<nbk, 256, 0, stream>>>(bbase, bcnt, ebuf, dinv, n);

    k_proj1<<<(n + 255) / 256, 256, 0, stream>>>(X, W1, dinv, B1, n);
    k_gagg1<<<nbk, 512, 0, stream>>>(bbase, bcnt, ebuf, B1, dinv, b1, B2, n);
    k_gagg2<<<nbk, 512, 0, stream>>>(bbase, bcnt, ebuf, B2, dinv, W2, b2, out, n);
}